// Round 7
// baseline (151.527 us; speedup 1.0000x reference)
//
#include <hip/hip_runtime.h>

// YOLO v1 loss, fp32. preds/labels: [B, 7, 7, 30] fp32. Output: scalar fp32.
// r1 structure (direct loads, no LDS, no fences) but 8 wide loads per
// cell/array instead of 15 float2: parity-dependent aligned layout
//   even cell (base 16B-aligned): 7x float4 @ {0,16,..,96} + float2 @ 112
//   odd  cell (base  8B-aligned): float2 @ 0 + 7x float4 @ {8,24,..,104}
// -> ~1.8x fewer L1 line-transactions per wave (the measured bottleneck).
// Fused deterministic last-block finalize.

#define LAMBDA_COORD 5.0f
#define LAMBDA_NOOBJ 0.5f

__device__ __forceinline__ float iou_xywh10(const float* b1, const float* b2) {
    float b1x1 = b1[0] - b1[2] * 0.5f;
    float b1y1 = b1[1] - b1[3] * 0.5f;
    float b1x2 = b1[0] + b1[2] * 0.5f;
    float b1y2 = b1[1] + b1[3] * 0.5f;
    float b2x1 = b2[0] - b2[2] * 0.5f;
    float b2y1 = b2[1] - b2[3] * 0.5f;
    float b2x2 = b2[0] + b2[2] * 0.5f;
    float b2y2 = b2[1] + b2[3] * 0.5f;
    float iw = fmaxf(fminf(b1x2, b2x2) - fmaxf(b1x1, b2x1), 0.0f);
    float ih = fmaxf(fminf(b1y2, b2y2) - fmaxf(b1y1, b2y1), 0.0f);
    float inter = iw * ih;
    float area1 = (b1x2 - b1x1) * (b1y2 - b1y1);
    float area2 = (b2x2 - b2x1) * (b2y2 - b2y1);
    return inter / (area1 + area2 - inter + 1e-10f);
}

// loss from the first 10 floats (p,l) + precomputed class-sum
__device__ __forceinline__ float cell_loss10(const float* __restrict__ p,
                                             const float* __restrict__ l,
                                             float cls) {
    bool obj  = (l[4] == 1.0f);
    float iou1 = iou_xywh10(p + 0, l + 0);
    float iou2 = iou_xywh10(p + 5, l + 0);
    bool box1 = (iou1 > iou2);

    float dx1 = l[0] - p[0], dy1 = l[1] - p[1];
    float xy1 = dx1 * dx1 + dy1 * dy1;
    float dx2 = l[5] - p[5], dy2 = l[6] - p[6];
    float xy2 = dx2 * dx2 + dy2 * dy2;

    float dw1 = sqrtf(l[2]) - sqrtf(p[2]);
    float dh1 = sqrtf(l[3]) - sqrtf(p[3]);
    float wh1 = dw1 * dw1 + dh1 * dh1;
    float dw2 = sqrtf(l[7]) - sqrtf(p[7]);
    float dh2 = sqrtf(l[8]) - sqrtf(p[8]);
    float wh2 = dw2 * dw2 + dh2 * dh2;

    float dc1 = l[4] - p[4];
    float conf1 = dc1 * dc1;
    float dc2 = l[9] - p[9];
    float conf2 = dc2 * dc2;

    if (obj) {
        float xy  = box1 ? xy1 : xy2;
        float wh  = box1 ? wh1 : wh2;
        float cf  = box1 ? conf1 : conf2;
        float no  = box1 ? p[9] * p[9] : p[4] * p[4];
        return LAMBDA_COORD * (xy + wh) + cf + LAMBDA_NOOBJ * no + cls;
    } else {
        return LAMBDA_NOOBJ * (p[4] * p[4] + p[9] * p[9]);
    }
}

// first-10 extraction from the parity-dependent register layout
__device__ __forceinline__ void extract10(const float4* __restrict__ f,
                                          float2 e, bool odd,
                                          float* __restrict__ v) {
    v[0] = odd ? e.x    : f[0].x;
    v[1] = odd ? e.y    : f[0].y;
    v[2] = odd ? f[0].x : f[0].z;
    v[3] = odd ? f[0].y : f[0].w;
    v[4] = odd ? f[0].z : f[1].x;
    v[5] = odd ? f[0].w : f[1].y;
    v[6] = odd ? f[1].x : f[1].z;
    v[7] = odd ? f[1].y : f[1].w;
    v[8] = odd ? f[1].z : f[2].x;
    v[9] = odd ? f[1].w : f[2].y;
}

__device__ __forceinline__ float block_reduce_sum(float v, float* smem) {
    #pragma unroll
    for (int off = 32; off > 0; off >>= 1)
        v += __shfl_down(v, off, 64);
    int lane = threadIdx.x & 63;
    int wid  = threadIdx.x >> 6;
    if (lane == 0) smem[wid] = v;
    __syncthreads();
    float total = 0.0f;
    if (threadIdx.x == 0) {
        int nw = blockDim.x >> 6;
        for (int i = 0; i < nw; ++i) total += smem[i];
    }
    return total;  // valid only on thread 0
}

__global__ void __launch_bounds__(256, 2) yolo_loss(
        const float* __restrict__ preds,
        const float* __restrict__ labels,
        float* __restrict__ out,
        float* __restrict__ partial,
        unsigned int* __restrict__ counter,
        int ncells, float inv_batch) {
    __shared__ float smem[4];
    __shared__ float smem2[4];
    __shared__ int is_last;

    int tid = threadIdx.x;
    float acc = 0.0f;
    int stride = gridDim.x * blockDim.x;

    for (int c = blockIdx.x * blockDim.x + tid; c < ncells; c += stride) {
        const char* pb = (const char*)preds  + (size_t)c * 120u;
        const char* lb = (const char*)labels + (size_t)c * 120u;
        bool odd = (c & 1);
        unsigned o4 = odd ? 8u : 0u;     // float4 run base (16B-aligned)
        unsigned o2 = odd ? 0u : 112u;   // float2 position (8B-aligned)

        const float4* p4 = reinterpret_cast<const float4*>(pb + o4);
        const float2* p2 = reinterpret_cast<const float2*>(pb + o2);
        const float4* l4 = reinterpret_cast<const float4*>(lb + o4);
        const float2* l2 = reinterpret_cast<const float2*>(lb + o2);

        float4 pf[7], lf[7];
        float2 pe, le;
        #pragma unroll
        for (int i = 0; i < 7; ++i) pf[i] = p4[i];
        pe = *p2;
        #pragma unroll
        for (int i = 0; i < 7; ++i) lf[i] = l4[i];
        le = *l2;

        // class-sum (indices 10..29, order-free):
        // common part: f[3..6] in both parities
        float cls = 0.0f;
        #pragma unroll
        for (int i = 3; i < 7; ++i) {
            float d0 = lf[i].x - pf[i].x;
            float d1 = lf[i].y - pf[i].y;
            float d2 = lf[i].z - pf[i].z;
            float d3 = lf[i].w - pf[i].w;
            cls = fmaf(d0, d0, cls);
            cls = fmaf(d1, d1, cls);
            cls = fmaf(d2, d2, cls);
            cls = fmaf(d3, d3, cls);
        }
        // boundary terms: even -> f[2].zw + e.xy ; odd -> f[2].xyzw
        float da0 = lf[2].x - pf[2].x, da1 = lf[2].y - pf[2].y;
        float a = da0 * da0 + da1 * da1;          // f[2].xy
        float db0 = lf[2].z - pf[2].z, db1 = lf[2].w - pf[2].w;
        float b = db0 * db0 + db1 * db1;          // f[2].zw
        float dt0 = le.x - pe.x, dt1 = le.y - pe.y;
        float t = dt0 * dt0 + dt1 * dt1;          // e.xy
        cls += b + (odd ? a : t);

        float pv[10], lv[10];
        extract10(pf, pe, odd, pv);
        extract10(lf, le, odd, lv);

        acc += cell_loss10(pv, lv, cls);
    }

    float bsum = block_reduce_sum(acc, smem);
    if (tid == 0) {
        partial[blockIdx.x] = bsum;
        __threadfence();
        unsigned int prev = atomicAdd(counter, 1u);
        is_last = (prev == gridDim.x - 1) ? 1 : 0;
    }
    __syncthreads();

    if (is_last) {
        __threadfence();
        float a = 0.0f;
        for (int i = tid; i < (int)gridDim.x; i += blockDim.x)
            a += partial[i];                   // fixed order -> deterministic
        float total = block_reduce_sum(a, smem2);
        if (tid == 0) out[0] = total * inv_batch;
    }
}

extern "C" void kernel_launch(void* const* d_in, const int* in_sizes, int n_in,
                              void* d_out, int out_size, void* d_ws, size_t ws_size,
                              hipStream_t stream) {
    const float* preds  = (const float*)d_in[0];
    const float* labels = (const float*)d_in[1];
    float* out = (float*)d_out;

    int ncells = in_sizes[0] / 30;             // B * 7 * 7
    int batch  = ncells / 49;
    float inv_batch = 1.0f / (float)batch;

    const int block = 256;
    int grid = (ncells + block - 1) / block;   // 3136 at B=16384
    int maxblocks = (int)((ws_size - sizeof(unsigned int)) / sizeof(float));
    if (grid > maxblocks) grid = maxblocks;    // grid-stride covers the rest
    if (grid > 8192) grid = 8192;
    if (grid < 1) grid = 1;

    float* partial = (float*)d_ws;
    unsigned int* counter = (unsigned int*)((char*)d_ws + (size_t)grid * sizeof(float));

    hipMemsetAsync(counter, 0, sizeof(unsigned int), stream);
    yolo_loss<<<grid, block, 0, stream>>>(preds, labels, out, partial, counter,
                                          ncells, inv_batch);
}